// Round 16
// baseline (4713.666 us; speedup 1.0000x reference)
//
#include <hip/hip_runtime.h>

#define NHID   128
#define NSTEPS 512
#define NSAMP  4096
#define SPB    16
#define BS     256
#define NBLK   (NSAMP / SPB)          // 256 blocks, 1 per CU
#define KL     20                     // k4-chunks of W staged in LDS (of 32)
#define SAMP_ELEMS (NSAMP * NSTEPS)
#define WT_ELEMS   (3 * NHID * NHID)  // packed weights, 196 KB

typedef float v2f __attribute__((ext_vector_type(2)));
typedef float v4f __attribute__((ext_vector_type(4)));

// packed fma, broadcast LOW half of weight pair to both lanes:
#define PK_LO(ACC, W2, H2) \
    asm("v_pk_fma_f32 %0, %1, %2, %0 op_sel:[0,0,0] op_sel_hi:[0,1,1]" \
        : "+v"(ACC) : "v"(W2), "v"(H2))
// broadcast HIGH half:
#define PK_HI(ACC, W2, H2) \
    asm("v_pk_fma_f32 %0, %1, %2, %0 op_sel:[1,0,0] op_sel_hi:[1,1,1]" \
        : "+v"(ACC) : "v"(W2), "v"(H2))

template<int IMM>
__device__ __forceinline__ float swz(float x) {
    return __int_as_float(__builtin_amdgcn_ds_swizzle(__float_as_int(x), IMM));
}

// wt[g][k4][c][j] = rk[(4*k4+j)*384 + g*128 + c]  (R8 packing)
__global__ __launch_bounds__(256)
void pack_w_kernel(const float* __restrict__ rk, float* __restrict__ wt) {
    const int i = blockIdx.x * 256 + threadIdx.x;
    if (i < WT_ELEMS) {
        const int j  = i & 3;
        const int c  = (i >> 2) & 127;
        const int k4 = (i >> 9) & 31;
        const int g  = i >> 14;
        wt[i] = rk[(k4 * 4 + j) * 384 + g * NHID + c];
    }
}

// 24 pk_fma for one channel's k4 (h0..h3 shared across channels)
#define GEMM_CH(WZ, WR, WH, AZ01, AZ23, AR01, AR23, AH01, AH23) do {      \
    const v2f wzA = (WZ).xy, wzB = (WZ).zw;                               \
    const v2f wrA = (WR).xy, wrB = (WR).zw;                               \
    const v2f whA = (WH).xy, whB = (WH).zw;                               \
    PK_LO(AZ01, wzA, h0.xy); PK_LO(AZ23, wzA, h0.zw);                     \
    PK_LO(AR01, wrA, h0.xy); PK_LO(AR23, wrA, h0.zw);                     \
    PK_LO(AH01, whA, h0.xy); PK_LO(AH23, whA, h0.zw);                     \
    PK_HI(AZ01, wzA, h1.xy); PK_HI(AZ23, wzA, h1.zw);                     \
    PK_HI(AR01, wrA, h1.xy); PK_HI(AR23, wrA, h1.zw);                     \
    PK_HI(AH01, whA, h1.xy); PK_HI(AH23, whA, h1.zw);                     \
    PK_LO(AZ01, wzB, h2.xy); PK_LO(AZ23, wzB, h2.zw);                     \
    PK_LO(AR01, wrB, h2.xy); PK_LO(AR23, wrB, h2.zw);                     \
    PK_LO(AH01, whB, h2.xy); PK_LO(AH23, whB, h2.zw);                     \
    PK_HI(AZ01, wzB, h3.xy); PK_HI(AZ23, wzB, h3.zw);                     \
    PK_HI(AR01, wrB, h3.xy); PK_HI(AR23, wrB, h3.zw);                     \
    PK_HI(AH01, whB, h3.xy); PK_HI(AH23, whB, h3.zw);                     \
} while (0)

template<int TR>
__global__ __launch_bounds__(BS, 1)
void vmc_gru_kernel(const float* __restrict__ gk,   // (2, 384)
                    const float* __restrict__ rk,   // (128, 384)
                    const float* __restrict__ gb,   // (2, 384)
                    const float* __restrict__ dw,   // (128, 2)
                    const float* __restrict__ db,   // (2,)
                    const float* __restrict__ u,    // (4096, 512)
                    const float* __restrict__ wt,   // packed (3,32,128,4)
                    float* __restrict__ out)        // samples then logp
{
    __shared__ v4f   slds[3 * KL * NHID];      // 120 KB, W chunk [g][k4<KL][c]
    __shared__ float hsm[2][NHID][SPB];        // 16 KB, double-buffered h[k][s]
    __shared__ float part[2][4][SPB][2];       // 1 KB

    const int tid = threadIdx.x;
    const int cg  = tid >> 2;                // channel group 0..63: owns cg, cg+64
    const int sq  = tid & 3;                 // sample-quad
    const int s0  = sq * 4;
    const int wv  = tid >> 6;                // wave 0..3
    const int sbase = blockIdx.x * SPB + s0;

    if (TR) {
        const v4f* wt4 = (const v4f*)wt;
        for (int i = tid; i < 3 * KL * NHID; i += BS) {
            const int g = i / (KL * NHID);
            const int r = i - g * (KL * NHID);
            slds[i] = wt4[g * 4096 + r];
        }
    }
    for (int i = tid; i < 2 * NHID * SPB; i += BS) (&hsm[0][0][0])[i] = 0.0f;
    __syncthreads();

    // per-channel constants for c0=cg and c1=cg+64
    const int c0 = cg, c1 = cg + 64;
    const float brzA = gb[384 + c0],       brzB = gb[384 + c1];
    const float brrA = gb[384 + 128 + c0], brrB = gb[384 + 128 + c1];
    const float brhA = gb[384 + 256 + c0], brhB = gb[384 + 256 + c1];
    const float xzIA = gb[c0],       xz0A = xzIA + gk[c0],       xz1A = xzIA + gk[384 + c0];
    const float xrIA = gb[128 + c0], xr0A = xrIA + gk[128 + c0], xr1A = xrIA + gk[384 + 128 + c0];
    const float xhIA = gb[256 + c0], xh0A = xhIA + gk[256 + c0], xh1A = xhIA + gk[384 + 256 + c0];
    const float xzIB = gb[c1],       xz0B = xzIB + gk[c1],       xz1B = xzIB + gk[384 + c1];
    const float xrIB = gb[128 + c1], xr0B = xrIB + gk[128 + c1], xr1B = xrIB + gk[384 + 128 + c1];
    const float xhIB = gb[256 + c1], xh0B = xhIB + gk[256 + c1], xh1B = xhIB + gk[384 + 256 + c1];
    const float dw0A = dw[c0 * 2], dw1A = dw[c0 * 2 + 1];
    const float dw0B = dw[c1 * 2], dw1B = dw[c1 * 2 + 1];
    const float db0 = db[0], db1 = db[1];

    const v4f* lzA = slds + c0;                    // LDS planes, channel A
    const v4f* lrA = slds + KL * 128 + c0;
    const v4f* lhA = slds + 2 * KL * 128 + c0;
    const v4f* gzA = (const v4f*)wt + c0;          // global planes
    const v4f* grA = (const v4f*)wt + 4096 + c0;
    const v4f* ghA = (const v4f*)wt + 8192 + c0;

    int   pv[4] = {0, 0, 0, 0};
    float lg[4] = {0.f, 0.f, 0.f, 0.f};
    float pr[4] = {1.f, 1.f, 1.f, 1.f};
    int cur = 0;

    for (int t = 0; t < NSTEPS; ++t) {
        float uv[4];
        #pragma unroll
        for (int j = 0; j < 4; ++j)
            uv[j] = u[(size_t)(sbase + j) * NSTEPS + t];

        v2f az01a = {brzA, brzA}, az23a = {brzA, brzA};
        v2f ar01a = {brrA, brrA}, ar23a = {brrA, brrA};
        v2f ah01a = {brhA, brhA}, ah23a = {brhA, brhA};
        v2f az01b = {brzB, brzB}, az23b = {brzB, brzB};
        v2f ar01b = {brrB, brrB}, ar23b = {brrB, brrB};
        v2f ah01b = {brhB, brhB}, ah23b = {brhB, brhB};
        const float* hb = &hsm[cur][0][0];

        if (TR) {
            #pragma unroll 4
            for (int k4 = 0; k4 < KL; ++k4) {         // W from LDS (both channels)
                const v4f h0 = *(const v4f*)(hb + (4*k4+0)*SPB + s0);
                const v4f h1 = *(const v4f*)(hb + (4*k4+1)*SPB + s0);
                const v4f h2 = *(const v4f*)(hb + (4*k4+2)*SPB + s0);
                const v4f h3 = *(const v4f*)(hb + (4*k4+3)*SPB + s0);
                const v4f wza = lzA[k4*128],      wzb = lzA[k4*128 + 64];
                const v4f wra = lrA[k4*128],      wrb = lrA[k4*128 + 64];
                const v4f wha = lhA[k4*128],      whb = lhA[k4*128 + 64];
                GEMM_CH(wza, wra, wha, az01a, az23a, ar01a, ar23a, ah01a, ah23a);
                GEMM_CH(wzb, wrb, whb, az01b, az23b, ar01b, ar23b, ah01b, ah23b);
            }
            #pragma unroll 4
            for (int k4 = KL; k4 < 32; ++k4) {        // W from L1/L2
                const v4f h0 = *(const v4f*)(hb + (4*k4+0)*SPB + s0);
                const v4f h1 = *(const v4f*)(hb + (4*k4+1)*SPB + s0);
                const v4f h2 = *(const v4f*)(hb + (4*k4+2)*SPB + s0);
                const v4f h3 = *(const v4f*)(hb + (4*k4+3)*SPB + s0);
                const v4f wza = gzA[k4*128],      wzb = gzA[k4*128 + 64];
                const v4f wra = grA[k4*128],      wrb = grA[k4*128 + 64];
                const v4f wha = ghA[k4*128],      whb = ghA[k4*128 + 64];
                GEMM_CH(wza, wra, wha, az01a, az23a, ar01a, ar23a, ah01a, ah23a);
                GEMM_CH(wzb, wrb, whb, az01b, az23b, ar01b, ar23b, ah01b, ah23b);
            }
        } else {
            const float* wp = rk;
            #pragma unroll 4
            for (int k = 0; k < NHID; ++k) {
                const v4f hv = *(const v4f*)(hb + k * SPB + s0);
                const float hk[4] = {hv.x, hv.y, hv.z, hv.w};
                const float wzsA = wp[c0],       wzsB = wp[c1];
                const float wrsA = wp[128 + c0], wrsB = wp[128 + c1];
                const float whsA = wp[256 + c0], whsB = wp[256 + c1];
                float aza[4] = {az01a.x, az01a.y, az23a.x, az23a.y};
                float ara[4] = {ar01a.x, ar01a.y, ar23a.x, ar23a.y};
                float aha[4] = {ah01a.x, ah01a.y, ah23a.x, ah23a.y};
                float azb[4] = {az01b.x, az01b.y, az23b.x, az23b.y};
                float arb[4] = {ar01b.x, ar01b.y, ar23b.x, ar23b.y};
                float ahb[4] = {ah01b.x, ah01b.y, ah23b.x, ah23b.y};
                #pragma unroll
                for (int j = 0; j < 4; ++j) {
                    aza[j] = fmaf(wzsA, hk[j], aza[j]); ara[j] = fmaf(wrsA, hk[j], ara[j]);
                    aha[j] = fmaf(whsA, hk[j], aha[j]);
                    azb[j] = fmaf(wzsB, hk[j], azb[j]); arb[j] = fmaf(wrsB, hk[j], arb[j]);
                    ahb[j] = fmaf(whsB, hk[j], ahb[j]);
                }
                az01a = (v2f){aza[0], aza[1]}; az23a = (v2f){aza[2], aza[3]};
                ar01a = (v2f){ara[0], ara[1]}; ar23a = (v2f){ara[2], ara[3]};
                ah01a = (v2f){aha[0], aha[1]}; ah23a = (v2f){aha[2], aha[3]};
                az01b = (v2f){azb[0], azb[1]}; az23b = (v2f){azb[2], azb[3]};
                ar01b = (v2f){arb[0], arb[1]}; ar23b = (v2f){arb[2], arb[3]};
                ah01b = (v2f){ahb[0], ahb[1]}; ah23b = (v2f){ahb[2], ahb[3]};
                wp += 384;
            }
        }

        const float azA[4] = {az01a.x, az01a.y, az23a.x, az23a.y};
        const float arA[4] = {ar01a.x, ar01a.y, ar23a.x, ar23a.y};
        const float ahA[4] = {ah01a.x, ah01a.y, ah23a.x, ah23a.y};
        const float azB[4] = {az01b.x, az01b.y, az23b.x, az23b.y};
        const float arB[4] = {ar01b.x, ar01b.y, ar23b.x, ar23b.y};
        const float ahB[4] = {ah01b.x, ah01b.y, ah23b.x, ah23b.y};

        // ---- gates + state update for both channels
        const v4f hoA = *(const v4f*)(hb + c0 * SPB + s0);
        const v4f hoB = *(const v4f*)(hb + c1 * SPB + s0);
        const float hovA[4] = {hoA.x, hoA.y, hoA.z, hoA.w};
        const float hovB[4] = {hoB.x, hoB.y, hoB.z, hoB.w};
        float hnA[4], hnB[4], p0s[4], p1s[4];
        #pragma unroll
        for (int j = 0; j < 4; ++j) {
            float xzA = pv[j] ? xz1A : xz0A, xzB = pv[j] ? xz1B : xz0B;
            float xrA = pv[j] ? xr1A : xr0A, xrB = pv[j] ? xr1B : xr0B;
            float xhA = pv[j] ? xh1A : xh0A, xhB = pv[j] ? xh1B : xh0B;
            if (t == 0) { xzA = xzIA; xrA = xrIA; xhA = xhIA;
                          xzB = xzIB; xrB = xrIB; xhB = xhIB; }
            const float zA  = 1.0f / (1.0f + expf(-(xzA + azA[j])));
            const float rA  = 1.0f / (1.0f + expf(-(xrA + arA[j])));
            const float hcA = tanhf(xhA + rA * ahA[j]);
            const float hA2 = zA * hovA[j] + (1.0f - zA) * hcA;
            const float zB  = 1.0f / (1.0f + expf(-(xzB + azB[j])));
            const float rB  = 1.0f / (1.0f + expf(-(xrB + arB[j])));
            const float hcB = tanhf(xhB + rB * ahB[j]);
            const float hB2 = zB * hovB[j] + (1.0f - zB) * hcB;
            hnA[j] = hA2;
            hnB[j] = hB2;
            p0s[j] = fmaf(hB2, dw0B, hA2 * dw0A);
            p1s[j] = fmaf(hB2, dw1B, hA2 * dw1A);
        }
        *(v4f*)&hsm[cur ^ 1][c0][s0] = (v4f){hnA[0], hnA[1], hnA[2], hnA[3]};
        *(v4f*)&hsm[cur ^ 1][c1][s0] = (v4f){hnB[0], hnB[1], hnB[2], hnB[3]};

        // butterfly over 16 channel-groups (lane bits 2..5) + xor32 — R8 tree
        #pragma unroll
        for (int j = 0; j < 4; ++j) {
            p0s[j] += swz<0x101F>(p0s[j]);  p1s[j] += swz<0x101F>(p1s[j]);
            p0s[j] += swz<0x201F>(p0s[j]);  p1s[j] += swz<0x201F>(p1s[j]);
            p0s[j] += swz<0x401F>(p0s[j]);  p1s[j] += swz<0x401F>(p1s[j]);
            p0s[j] += __shfl_xor(p0s[j], 32);
            p1s[j] += __shfl_xor(p1s[j], 32);
        }
        const int pb = t & 1;
        if ((tid & 63) < 4) {
            *(float4*)&part[pb][wv][s0][0]     = make_float4(p0s[0], p1s[0], p0s[1], p1s[1]);
            *(float4*)&part[pb][wv][s0 + 2][0] = make_float4(p0s[2], p1s[2], p0s[3], p1s[3]);
        }
        __syncthreads();   // single barrier: h_new + partials visible

        // ---- redundant logit/sample phase (4-wave ascending fold)
        float l0[4] = {db0, db0, db0, db0};
        float l1[4] = {db1, db1, db1, db1};
        #pragma unroll
        for (int w = 0; w < 4; ++w) {
            const float4 qa = *(const float4*)&part[pb][w][s0][0];
            const float4 qb = *(const float4*)&part[pb][w][s0 + 2][0];
            l0[0] += qa.x; l1[0] += qa.y;
            l0[1] += qa.z; l1[1] += qa.w;
            l0[2] += qb.x; l1[2] += qb.y;
            l0[3] += qb.z; l1[3] += qb.w;
        }
        #pragma unroll
        for (int j = 0; j < 4; ++j) {
            const float mx = fmaxf(l0[j], l1[j]);
            const float e0 = expf(l0[j] - mx);
            const float e1 = expf(l1[j] - mx);
            const float inv = 1.0f / (e0 + e1);
            const float p1v = e1 * inv;
            const int st = (uv[j] < p1v) ? 1 : 0;
            const float psel = st ? p1v : (e0 * inv);
            pr[j] *= (psel + 1e-10f);
            pv[j] = st;
            if (cg == 0)
                out[(size_t)(sbase + j) * NSTEPS + t] = (float)st;
        }
        if ((t & 7) == 7) {
            #pragma unroll
            for (int j = 0; j < 4; ++j) { lg[j] += logf(pr[j]); pr[j] = 1.0f; }
        }
        cur ^= 1;
    }

    if (cg == 0) {
        #pragma unroll
        for (int j = 0; j < 4; ++j)
            out[SAMP_ELEMS + sbase + j] = lg[j];
    }
}

extern "C" void kernel_launch(void* const* d_in, const int* in_sizes, int n_in,
                              void* d_out, int out_size, void* d_ws, size_t ws_size,
                              hipStream_t stream) {
    const float* gk = (const float*)d_in[0];
    const float* rk = (const float*)d_in[1];
    const float* gb = (const float*)d_in[2];
    const float* dw = (const float*)d_in[3];
    const float* db = (const float*)d_in[4];
    const float* u  = (const float*)d_in[5];
    float* out = (float*)d_out;

    if (ws_size >= (size_t)WT_ELEMS * sizeof(float)) {
        float* wt = (float*)d_ws;
        pack_w_kernel<<<(WT_ELEMS + 255) / 256, 256, 0, stream>>>(rk, wt);
        vmc_gru_kernel<1><<<NBLK, BS, 0, stream>>>(gk, rk, gb, dw, db, u, wt, out);
    } else {
        vmc_gru_kernel<0><<<NBLK, BS, 0, stream>>>(gk, rk, gb, dw, db, u, rk, out);
    }
}